// Round 10
// baseline (202.936 us; speedup 1.0000x reference)
//
#include <hip/hip_runtime.h>
#include <hip/hip_bf16.h>
#include <math.h>

// B=32768, L=24, H=64, V=64
#define B_SZ 32768
#define L_SZ 24
#define H_SZ 64
#define V_SZ 64

// ws layout (dword offsets) — scan blob [G|WKTH|WKTL|TAIL] unchanged from R7/R9
#define G_O     8192     // G[64][64] f32
#define WKTH_O  12288    // WkT hi bf16 [64][72]
#define WKTL_O  14592    // WkT lo bf16 [64][72]
#define TAIL_O  16896    // nrm[64] | b2[64] | cf[32]
#define WS_DW   17056

// k_scan LDS layout (dwords) — unchanged from R7/R9
#define G_L     0
#define WKTH_L  4096
#define WKTL_L  6400
#define TAIL_L  8704
#define W32_L   8864     // W accum f32 [64][64]
#define WH_L    12960    // W hi bf16 [64][72]
#define WL_L    15264    // W lo bf16 [64][72]
#define LDS_DW  17568    // 70.3 KB -> 2 blocks/CU

// k_prep LDS layout (dwords)
#define W1_P    0        // w1[64][128]
#define W2_P    8192     // w2[128][64]
#define RP_P    16384    // rp_w[64][64]
#define OW_P    20480    // out_w[64][64]
#define KN_P    24576    // kn[64][64]
#define PREP_DW 28672    // 114.7 KB (single block)

typedef __attribute__((ext_vector_type(8))) short short8v;
typedef __attribute__((ext_vector_type(4))) float f32x4;

static __device__ __forceinline__ unsigned short bf_hi(float x) {
  const unsigned b = __float_as_uint(x);
  return (unsigned short)((b + 0x7FFF + ((b >> 16) & 1)) >> 16);  // RNE
}

// ---------------------------------------------------------------------------
// Kernel 1: fused prep, ONE block x 256 threads.
// Stage w1|w2|rp_w|out_w into LDS (one latency round-trip); wave wv computes
// vocab rows wv*16..wv*16+15 with the validated R1-R9 shfl-matvec sequence
// (identical FMA order); kn -> LDS; WkT hi/lo scattered transposed to ws;
// then G rows via the validated k_gw shfl pattern; b2 + cf tail.
// ---------------------------------------------------------------------------
__global__ __launch_bounds__(256) void k_prep(
    const float* __restrict__ embed, const float* __restrict__ w1, const float* __restrict__ b1,
    const float* __restrict__ w2, const float* __restrict__ b2,
    const float* __restrict__ ln_g, const float* __restrict__ ln_b,
    const float* __restrict__ rp_w, const float* __restrict__ rp_b,
    const float* __restrict__ out_w, const float* __restrict__ out_b,
    const float* __restrict__ alpha_logits, float* __restrict__ ws)
{
  __shared__ float L[PREP_DW];
  const int tid = threadIdx.x;

  // ---- stage all weights (24 float4/thread, one round trip) ----
  {
    const float4* s1 = (const float4*)w1;
    const float4* s2 = (const float4*)w2;
    const float4* sr = (const float4*)rp_w;
    const float4* so = (const float4*)out_w;
    float4 r1[8], r2[8], rr[4], ro[4];
    #pragma unroll
    for (int i = 0; i < 8; ++i) r1[i] = s1[tid + 256 * i];
    #pragma unroll
    for (int i = 0; i < 8; ++i) r2[i] = s2[tid + 256 * i];
    #pragma unroll
    for (int i = 0; i < 4; ++i) rr[i] = sr[tid + 256 * i];
    #pragma unroll
    for (int i = 0; i < 4; ++i) ro[i] = so[tid + 256 * i];
    #pragma unroll
    for (int i = 0; i < 8; ++i) ((float4*)(L + W1_P))[tid + 256 * i] = r1[i];
    #pragma unroll
    for (int i = 0; i < 8; ++i) ((float4*)(L + W2_P))[tid + 256 * i] = r2[i];
    #pragma unroll
    for (int i = 0; i < 4; ++i) ((float4*)(L + RP_P))[tid + 256 * i] = rr[i];
    #pragma unroll
    for (int i = 0; i < 4; ++i) ((float4*)(L + OW_P))[tid + 256 * i] = ro[i];
  }
  __syncthreads();

  const int j = tid & 63;
  const int wv = tid >> 6;
  const float* w1L = L + W1_P;
  const float* w2L = L + W2_P;
  const float* rpL = L + RP_P;
  const float* owL = L + OW_P;
  unsigned short* wsu = (unsigned short*)ws;

  // loop-invariant scalars + all 16 embed elements (one round trip)
  const float b1a = b1[j], b1b = b1[j + 64], b2j = b2[j];
  const float lgj = ln_g[j], lbj = ln_b[j];
  float evs[16];
  #pragma unroll
  for (int r = 0; r < 16; ++r) evs[r] = embed[(wv * 16 + r) * H_SZ + j];

  #pragma unroll 4
  for (int r = 0; r < 16; ++r) {
    const int v = wv * 16 + r;
    const float ev = evs[r];
    float h0 = b1a, h1 = b1b;
    #pragma unroll
    for (int k = 0; k < H_SZ; ++k) {
      const float ek = __shfl(ev, k);
      h0 = fmaf(ek, w1L[k * 128 + j], h0);
      h1 = fmaf(ek, w1L[k * 128 + 64 + j], h1);
    }
    h0 = fmaxf(h0, 0.0f);
    h1 = fmaxf(h1, 0.0f);
    float x = ev + b2j;
    #pragma unroll
    for (int k = 0; k < H_SZ; ++k) {
      x = fmaf(__shfl(h0, k), w2L[k * H_SZ + j], x);
      x = fmaf(__shfl(h1, k), w2L[(k + 64) * H_SZ + j], x);
    }
    float mu = x;
    #pragma unroll
    for (int m = 1; m < 64; m <<= 1) mu += __shfl_xor(mu, m);
    mu *= (1.0f / 64.0f);
    const float dv = x - mu;
    float var = dv * dv;
    #pragma unroll
    for (int m = 1; m < 64; m <<= 1) var += __shfl_xor(var, m);
    var *= (1.0f / 64.0f);
    const float y = dv * rsqrtf(var + 1e-5f) * lgj + lbj;
    float n2 = y * y;
    #pragma unroll
    for (int m = 1; m < 64; m <<= 1) n2 += __shfl_xor(n2, m);
    const float nrm = sqrtf(n2);
    const float rn = 1.0f / fmaxf(nrm, 1e-12f);
    L[KN_P + v * H_SZ + j] = y * rn;
    if (j == 0) ws[TAIL_O + v] = nrm;
    float t1 = 0.0f;
    #pragma unroll
    for (int k = 0; k < H_SZ; ++k) t1 = fmaf(__shfl(y, k), rpL[k * H_SZ + j], t1);
    float wk = 0.0f;
    #pragma unroll
    for (int k = 0; k < H_SZ; ++k) wk = fmaf(__shfl(t1, k), owL[k * H_SZ + j], wk);
    // WkT[j][v] = Wk[v][j], split hi/lo (identical values to R7/R9 k_gw)
    const unsigned short hi = bf_hi(wk);
    const float fhi = __uint_as_float((unsigned)hi << 16);
    const unsigned short lo = bf_hi(wk - fhi);
    wsu[WKTH_O * 2 + j * 72 + v] = hi;
    wsu[WKTL_O * 2 + j * 72 + v] = lo;
  }
  __syncthreads();

  // ---- G rows (identical shfl pattern to validated k_gw) ----
  {
    float rreg[64];
    const float4* rp4 = (const float4*)(L + KN_P + j * H_SZ);
    #pragma unroll
    for (int i = 0; i < 16; ++i) {
      const float4 f = rp4[i];
      rreg[4 * i] = f.x; rreg[4 * i + 1] = f.y; rreg[4 * i + 2] = f.z; rreg[4 * i + 3] = f.w;
    }
    #pragma unroll
    for (int r = 0; r < 16; ++r) {
      const int u = wv * 16 + r;
      const float a = L[KN_P + u * H_SZ + j];
      float s = 0.0f;
      #pragma unroll
      for (int k = 0; k < 64; ++k) s = fmaf(__shfl(a, k), rreg[k], s);
      ws[G_O + u * H_SZ + j] = s;
    }
  }

  // ---- tail: b2 (wave 0), cf (wave 1) ----
  if (wv == 0) {
    float s = out_b[j];
    #pragma unroll
    for (int k = 0; k < H_SZ; ++k) s = fmaf(rp_b[k], owL[k * H_SZ + j], s);
    ws[TAIL_O + 64 + j] = s;
  } else if (wv == 1 && j < 32) {
    float cf = 0.0f;
    if (j < L_SZ - 1) {
      const float a = 1.0f / (1.0f + expf(-alpha_logits[j])) * 0.49f + 0.5f;
      cf = 1.0f - a;
    }
    ws[TAIL_O + 128 + j] = cf;
  }
}

// ---------------------------------------------------------------------------
// Kernel 2: scan — byte-identical to the validated R7/R9 version.
// ---------------------------------------------------------------------------
__global__ __launch_bounds__(256) void k_scan(
    const int* __restrict__ seq, const float* __restrict__ ws, float* __restrict__ out)
{
  __shared__ float lds[LDS_DW];
  const int tid = threadIdx.x;
  const float4* ws4 = (const float4*)ws;
  float4* l4 = (float4*)lds;
  for (int i = tid; i < (WS_DW - 8192) / 4; i += 256) l4[i] = ws4[2048 + i];
  const float4 z4 = {0.f, 0.f, 0.f, 0.f};
  for (int i = tid; i < 1024; i += 256) ((float4*)(lds + W32_L))[i] = z4;
  __syncthreads();

  const int lane = tid & 63;
  const int wv = tid >> 6;
  const int batch0 = blockIdx.x * 64;
  const float* Gt = lds + G_L;

  // ---- Phase A ----
  if (lane < 16) {
    const int ab = wv * 16 + lane;
    int g[24];
    const int4* sp = (const int4*)(seq + (batch0 + ab) * L_SZ);
    #pragma unroll
    for (int i = 0; i < 6; ++i) {
      const int4 t4 = sp[i];
      g[4 * i] = t4.x; g[4 * i + 1] = t4.y; g[4 * i + 2] = t4.z; g[4 * i + 3] = t4.w;
    }
    const int q = g[23];
    const float nl = lds[TAIL_L + q];
    float cfv[24];
    #pragma unroll
    for (int i = 0; i < 6; ++i) {
      const float4 f = ((const float4*)(lds + TAIL_L + 128))[i];
      cfv[4 * i] = f.x; cfv[4 * i + 1] = f.y; cfv[4 * i + 2] = f.z; cfv[4 * i + 3] = f.w;
    }
    float P[23], carr[23];
    #pragma unroll
    for (int t = 0; t < 23; ++t) P[t] = 0.0f;
    #pragma unroll
    for (int s = 22; s >= 0; --s) {
      const float base = nl * Gt[(g[s] << 6) + q];
      const float cs = cfv[s] * (base - P[s]);
      carr[s] = cs;
      #pragma unroll
      for (int t = 0; t < s; ++t)
        P[t] = fmaf(cs, Gt[(g[t] << 6) + g[s]], P[t]);
    }
    float* wrow = lds + W32_L + ab * 64;
    #pragma unroll
    for (int t = 0; t < 23; ++t)
      atomicAdd(&wrow[g[t]], carr[t]);
  }
  __syncthreads();

  // ---- Convert W32 -> WH/WL ----
  {
    const int c4 = (lane & 15) * 4;
    unsigned short* whp = (unsigned short*)(lds + WH_L);
    unsigned short* wlp = (unsigned short*)(lds + WL_L);
    #pragma unroll
    for (int i = 0; i < 4; ++i) {
      const int row = wv * 16 + (lane >> 4) + i * 4;
      const float4 f = *(const float4*)(lds + W32_L + row * 64 + c4);
      ushort4 h, l2;
      h.x = bf_hi(f.x); h.y = bf_hi(f.y); h.z = bf_hi(f.z); h.w = bf_hi(f.w);
      l2.x = bf_hi(f.x - __uint_as_float((unsigned)h.x << 16));
      l2.y = bf_hi(f.y - __uint_as_float((unsigned)h.y << 16));
      l2.z = bf_hi(f.z - __uint_as_float((unsigned)h.z << 16));
      l2.w = bf_hi(f.w - __uint_as_float((unsigned)h.w << 16));
      *(ushort4*)(whp + row * 72 + c4) = h;
      *(ushort4*)(wlp + row * 72 + c4) = l2;
    }
  }
  __syncthreads();

  // ---- Phase B: MFMA ----
  {
    const int cl = lane & 15;
    const int q4 = lane >> 4;
    const unsigned short* whp = (const unsigned short*)(lds + WH_L);
    const unsigned short* wlp = (const unsigned short*)(lds + WL_L);
    const unsigned short* bhp = (const unsigned short*)(lds + WKTH_L);
    const unsigned short* blp = (const unsigned short*)(lds + WKTL_L);

    const int arow = wv * 16 + cl;
    const short8v ah0 = *(const short8v*)(whp + arow * 72 + q4 * 8);
    const short8v ah1 = *(const short8v*)(whp + arow * 72 + 32 + q4 * 8);
    const short8v al0 = *(const short8v*)(wlp + arow * 72 + q4 * 8);
    const short8v al1 = *(const short8v*)(wlp + arow * 72 + 32 + q4 * 8);

    #pragma unroll
    for (int ct = 0; ct < 4; ++ct) {
      const int col = ct * 16 + cl;
      const short8v bh0 = *(const short8v*)(bhp + col * 72 + q4 * 8);
      const short8v bh1 = *(const short8v*)(bhp + col * 72 + 32 + q4 * 8);
      const short8v bl0 = *(const short8v*)(blp + col * 72 + q4 * 8);
      const short8v bl1 = *(const short8v*)(blp + col * 72 + 32 + q4 * 8);
      const float b2v = lds[TAIL_L + 64 + col];
      f32x4 acc = {b2v, b2v, b2v, b2v};
      acc = __builtin_amdgcn_mfma_f32_16x16x32_bf16(ah0, bh0, acc, 0, 0, 0);
      acc = __builtin_amdgcn_mfma_f32_16x16x32_bf16(ah1, bh1, acc, 0, 0, 0);
      acc = __builtin_amdgcn_mfma_f32_16x16x32_bf16(al0, bh0, acc, 0, 0, 0);
      acc = __builtin_amdgcn_mfma_f32_16x16x32_bf16(al1, bh1, acc, 0, 0, 0);
      acc = __builtin_amdgcn_mfma_f32_16x16x32_bf16(ah0, bl0, acc, 0, 0, 0);
      acc = __builtin_amdgcn_mfma_f32_16x16x32_bf16(ah1, bl1, acc, 0, 0, 0);
      #pragma unroll
      for (int rr = 0; rr < 4; ++rr)
        out[(batch0 + wv * 16 + q4 * 4 + rr) * V_SZ + col] = acc[rr];
    }
  }
}

// ---------------------------------------------------------------------------
extern "C" void kernel_launch(void* const* d_in, const int* in_sizes, int n_in,
                              void* d_out, int out_size, void* d_ws, size_t ws_size,
                              hipStream_t stream)
{
  const int*   seq          = (const int*)d_in[0];
  const float* embed        = (const float*)d_in[1];
  const float* w1           = (const float*)d_in[2];
  const float* b1           = (const float*)d_in[3];
  const float* w2           = (const float*)d_in[4];
  const float* b2           = (const float*)d_in[5];
  const float* ln_g         = (const float*)d_in[6];
  const float* ln_b         = (const float*)d_in[7];
  const float* rp_w         = (const float*)d_in[8];
  const float* rp_b         = (const float*)d_in[9];
  const float* out_w        = (const float*)d_in[10];
  const float* out_b        = (const float*)d_in[11];
  const float* alpha_logits = (const float*)d_in[12];
  float* ws   = (float*)d_ws;
  float* outp = (float*)d_out;

  hipLaunchKernelGGL(k_prep, dim3(1), dim3(256), 0, stream,
                     embed, w1, b1, w2, b2, ln_g, ln_b,
                     rp_w, rp_b, out_w, out_b, alpha_logits, ws);
  hipLaunchKernelGGL(k_scan, dim3(B_SZ / 64), dim3(256), 0, stream,
                     seq, ws, outp);
}